// Round 6
// baseline (524.687 us; speedup 1.0000x reference)
//
#include <hip/hip_runtime.h>
#include <hip/hip_bf16.h>

#define NN 50000
#define NE 800000
#define NG 128

typedef unsigned short u16;

__device__ __forceinline__ float lrelu(float x){ return x > 0.f ? x : 0.2f*x; }
__device__ __forceinline__ u16 f2bf(float f){
    __hip_bfloat16 h = __float2bfloat16(f);
    return *(u16*)&h;
}
// unpack 8 bf16 (as uint4) -> 8 floats
__device__ __forceinline__ void unpack8(uint4 t, float* f){
    f[0]=__uint_as_float(t.x<<16); f[1]=__uint_as_float(t.x&0xffff0000u);
    f[2]=__uint_as_float(t.y<<16); f[3]=__uint_as_float(t.y&0xffff0000u);
    f[4]=__uint_as_float(t.z<<16); f[5]=__uint_as_float(t.z&0xffff0000u);
    f[6]=__uint_as_float(t.w<<16); f[7]=__uint_as_float(t.w&0xffff0000u);
}

// ---------------- CSR build ----------------
__global__ void k_count(const int* __restrict__ dst, int* __restrict__ degi, int E){
    int e = blockIdx.x*blockDim.x + threadIdx.x;
    if (e < E) atomicAdd(&degi[dst[e]], 1);
}

__global__ void k_dinv(const int* __restrict__ degi, float* __restrict__ dinv, int n){
    int i = blockIdx.x*blockDim.x + threadIdx.x;
    if (i < n) dinv[i] = rsqrtf((float)(degi[i] + 1));   // +1 = self loop
}

// hierarchical scan: stage A — per-block local exclusive scan (1024 elems/block)
__global__ void k_scan_a(const int* __restrict__ deg, int* __restrict__ rowptr,
                         int* __restrict__ bsum, int n){
    __shared__ int lds[256];
    int base = blockIdx.x*1024 + threadIdx.x*4;
    int v[4]; int s = 0;
#pragma unroll
    for (int k=0;k<4;k++){ v[k] = (base+k < n) ? deg[base+k] : 0; s += v[k]; }
    lds[threadIdx.x] = s;
    __syncthreads();
    for (int off=1; off<256; off<<=1){
        int t = (threadIdx.x>=off) ? lds[threadIdx.x-off] : 0;
        __syncthreads(); lds[threadIdx.x] += t; __syncthreads();
    }
    int run = lds[threadIdx.x] - s;
#pragma unroll
    for (int k=0;k<4;k++){ if (base+k < n) rowptr[base+k] = run; run += v[k]; }
    if (threadIdx.x == 255) bsum[blockIdx.x] = lds[255];
}

__global__ void k_scan_b(int* __restrict__ bsum, int* __restrict__ rowptr, int nb, int n){
    __shared__ int lds[64];
    int s = (threadIdx.x < nb) ? bsum[threadIdx.x] : 0;
    lds[threadIdx.x] = s;
    __syncthreads();
    for (int off=1; off<64; off<<=1){
        int t = (threadIdx.x>=off) ? lds[threadIdx.x-off] : 0;
        __syncthreads(); lds[threadIdx.x] += t; __syncthreads();
    }
    if (threadIdx.x < nb) bsum[threadIdx.x] = lds[threadIdx.x] - s;
    if (threadIdx.x == 63) rowptr[n] = lds[63];
}

__global__ void k_scan_c(int* __restrict__ rowptr, const int* __restrict__ bsum, int n){
    int i = blockIdx.x*256 + threadIdx.x;
    int idx = i*4;
    int o = bsum[blockIdx.x];
#pragma unroll
    for (int k=0;k<4;k++) if (idx+k < n) rowptr[idx+k] += o;
}

__global__ void k_scatter(const int* __restrict__ src, const int* __restrict__ dst,
                          const int* __restrict__ rowptr, int* __restrict__ cursor,
                          int* __restrict__ csr_src, int E){
    int e = blockIdx.x*blockDim.x + threadIdx.x;
    if (e < E){
        int d = dst[e];
        int pos = rowptr[d] + atomicAdd(&cursor[d], 1);
        csr_src[pos] = src[e];
    }
}

// ---------------- small matmul (fp32 out) ----------------
template<int K, int M>
__global__ void k_mm(const float* __restrict__ in, int istride,
                     const float* __restrict__ W, float* __restrict__ out, int n){
    __shared__ float wl[K*M];
    for (int i = threadIdx.x; i < K*M; i += blockDim.x) wl[i] = W[i];
    __syncthreads();
    constexpr int NPB = 256 / M;
    int m  = threadIdx.x % M;
    int nl = threadIdx.x / M;
    int node = blockIdx.x * NPB + nl;
    if (node >= n) return;
    const float* row = in + (size_t)node * istride;
    float acc = 0.f;
#pragma unroll 8
    for (int k = 0; k < K; k++) acc += row[k] * wl[k*M + m];
    out[(size_t)node*M + m] = acc;
}

// bf16-out variant
template<int K, int M>
__global__ void k_mm_bf(const float* __restrict__ in, int istride,
                        const float* __restrict__ W, u16* __restrict__ out, int n){
    __shared__ float wl[K*M];
    for (int i = threadIdx.x; i < K*M; i += blockDim.x) wl[i] = W[i];
    __syncthreads();
    constexpr int NPB = 256 / M;
    int m  = threadIdx.x % M;
    int nl = threadIdx.x / M;
    int node = blockIdx.x * NPB + nl;
    if (node >= n) return;
    const float* row = in + (size_t)node * istride;
    float acc = 0.f;
#pragma unroll 8
    for (int k = 0; k < K; k++) acc += row[k] * wl[k*M + m];
    out[(size_t)node*M + m] = f2bf(acc);
}

// ---------------- mm4: [N,128] @ [128,256] -> bf16, 64x64 tiles ----------------
__global__ void k_mm4(const float* __restrict__ in, int istride,
                      const float* __restrict__ W, u16* __restrict__ out, int n){
    __shared__ __align__(16) float xs[64][68];
    __shared__ __align__(16) float ws[64][68];
    int tid = threadIdx.x;
    int tx = tid & 15;
    int ty = tid >> 4;
    int nbase = blockIdx.y * 64;
    int cbase = blockIdx.x * 64;
    float acc[4][4] = {};
    for (int kb = 0; kb < 128; kb += 64){
#pragma unroll
        for (int p = 0; p < 4; p++){
            int r = p*16 + ty;
            int nn = nbase + r;
            float4 v = make_float4(0.f,0.f,0.f,0.f);
            if (nn < n) v = *(const float4*)(in + (size_t)nn*istride + kb + tx*4);
            *(float4*)&xs[r][tx*4] = v;
            float4 wv = *(const float4*)(W + (size_t)(kb + r)*256 + cbase + tx*4);
            *(float4*)&ws[r][tx*4] = wv;
        }
        __syncthreads();
#pragma unroll 16
        for (int k = 0; k < 64; k++){
            float4 wv = *(const float4*)&ws[k][tx*4];
#pragma unroll
            for (int i2 = 0; i2 < 4; i2++){
                float a = xs[ty*4 + i2][k];
                acc[i2][0] += a*wv.x; acc[i2][1] += a*wv.y;
                acc[i2][2] += a*wv.z; acc[i2][3] += a*wv.w;
            }
        }
        __syncthreads();
    }
#pragma unroll
    for (int i2 = 0; i2 < 4; i2++){
        int nn = nbase + ty*4 + i2;
        if (nn < n){
            ushort4 v;
            v.x = f2bf(acc[i2][0]); v.y = f2bf(acc[i2][1]);
            v.z = f2bf(acc[i2][2]); v.w = f2bf(acc[i2][3]);
            *(ushort4*)(out + (size_t)nn*256 + cbase + tx*4) = v;
        }
    }
}

// ---------------- GCN aggregation: 16 lanes/node, edge loop unrolled x4 ----------------
template<int C>
__global__ void k_gcn_agg(const float* __restrict__ h, const float* __restrict__ dinv,
                          const int* __restrict__ rowptr, const int* __restrict__ csr_src,
                          const float* __restrict__ b, float* __restrict__ out,
                          int ostride, int n){
    constexpr int CL = C/4;          // chan-lanes (4 or 8)
    constexpr int S  = 16/CL;        // edge slots (4 or 2)
    int lin = threadIdx.x & 15;
    int i = blockIdx.x*16 + (threadIdx.x >> 4);
    if (i >= n) return;
    int ll = lin % CL, slot = lin / CL;
    float di = dinv[i];
    float acc[4] = {0.f,0.f,0.f,0.f};
    if (slot == 0){
        float4 t = ((const float4*)(h + (size_t)i*C))[ll];
        acc[0]=di*t.x; acc[1]=di*t.y; acc[2]=di*t.z; acc[3]=di*t.w;
    }
    int e0 = rowptr[i], e1 = rowptr[i+1];
    int e = e0 + slot;
    for (; e + 3*S < e1; e += 4*S){
        int j0 = csr_src[e], j1 = csr_src[e+S], j2 = csr_src[e+2*S], j3 = csr_src[e+3*S];
        float d0 = dinv[j0], d1 = dinv[j1], d2 = dinv[j2], d3 = dinv[j3];
        float4 t0 = ((const float4*)(h + (size_t)j0*C))[ll];
        float4 t1 = ((const float4*)(h + (size_t)j1*C))[ll];
        float4 t2 = ((const float4*)(h + (size_t)j2*C))[ll];
        float4 t3 = ((const float4*)(h + (size_t)j3*C))[ll];
        acc[0]+=d0*t0.x+d1*t1.x+d2*t2.x+d3*t3.x;
        acc[1]+=d0*t0.y+d1*t1.y+d2*t2.y+d3*t3.y;
        acc[2]+=d0*t0.z+d1*t1.z+d2*t2.z+d3*t3.z;
        acc[3]+=d0*t0.w+d1*t1.w+d2*t2.w+d3*t3.w;
    }
    for (; e < e1; e += S){
        int j = csr_src[e];
        float dj = dinv[j];
        float4 t = ((const float4*)(h + (size_t)j*C))[ll];
        acc[0]+=dj*t.x; acc[1]+=dj*t.y; acc[2]+=dj*t.z; acc[3]+=dj*t.w;
    }
#pragma unroll
    for (int m = CL; m < 16; m <<= 1){
#pragma unroll
        for (int k=0;k<4;k++) acc[k] += __shfl_xor(acc[k], m, 64);
    }
    if (slot == 0){
        float4 o;
        o.x = fmaxf(di*acc[0] + b[ll*4+0], 0.f);
        o.y = fmaxf(di*acc[1] + b[ll*4+1], 0.f);
        o.z = fmaxf(di*acc[2] + b[ll*4+2], 0.f);
        o.w = fmaxf(di*acc[3] + b[ll*4+3], 0.f);
        *(float4*)(out + (size_t)i*ostride + ll*4) = o;
    }
}

// ---------------- GAT attention coefficients (bf16 h, uint4 loads) ----------------
template<int H, int C>
__global__ void k_att(const u16* __restrict__ h, const float* __restrict__ att_s,
                      const float* __restrict__ att_d, float* __restrict__ asrc,
                      float* __restrict__ adst, int n){
    __shared__ float ss[H*C], sd[H*C];
    for (int k = threadIdx.x; k < H*C; k += 256){ ss[k]=att_s[k]; sd[k]=att_d[k]; }
    __syncthreads();
    int idx = blockIdx.x*256 + threadIdx.x;
    int i = idx / H, hh = idx % H;
    if (i >= n) return;
    const uint4* rp = (const uint4*)(h + (size_t)i*H*C + hh*C);
    float s=0.f, d=0.f;
#pragma unroll
    for (int q = 0; q < C/8; q++){
        float f[8]; unpack8(rp[q], f);
#pragma unroll
        for (int k=0;k<8;k++){ s += f[k]*ss[hh*C+q*8+k]; d += f[k]*sd[hh*C+q*8+k]; }
    }
    asrc[idx]=s; adst[idx]=d;
}

// ---------------- GAT aggregation: wave/node, edge loop unrolled x4, __expf ----------------
template<int H, int C>
__global__ void k_gat_agg(const u16* __restrict__ h, const float* __restrict__ asrc,
                          const float* __restrict__ adst, const int* __restrict__ rowptr,
                          const int* __restrict__ csr_src, const float* __restrict__ b,
                          float* __restrict__ out, int ostride, int n){
    constexpr int HC = H*C;          // 256 or 128
    constexpr int CL = HC/8;         // chan-lanes (32 or 16), 8 bf16 each
    constexpr int S  = 64/CL;        // edge slots (2 or 4)
    int lane = threadIdx.x & 63;
    int wid  = threadIdx.x >> 6;
    int i = blockIdx.x*4 + wid;
    if (i >= n) return;
    int ll   = lane % CL;
    int slot = lane / CL;
    int head = (ll*8)/C;
    float ad = adst[(size_t)i*H + head];
    float acc[8] = {0.f,0.f,0.f,0.f,0.f,0.f,0.f,0.f};
    float s = 0.f;
    if (slot == 0){
        float wself = __expf(lrelu(asrc[(size_t)i*H + head] + ad));
        uint4 t = ((const uint4*)(h + (size_t)i*HC))[ll];
        float f[8]; unpack8(t, f);
#pragma unroll
        for (int k=0;k<8;k++) acc[k] = wself*f[k];
        s = wself;
    }
    int e0 = rowptr[i], e1 = rowptr[i+1];
    int e = e0 + slot;
    for (; e + 3*S < e1; e += 4*S){
        int j0 = csr_src[e], j1 = csr_src[e+S], j2 = csr_src[e+2*S], j3 = csr_src[e+3*S];
        float w0 = __expf(lrelu(asrc[(size_t)j0*H + head] + ad));
        float w1 = __expf(lrelu(asrc[(size_t)j1*H + head] + ad));
        float w2 = __expf(lrelu(asrc[(size_t)j2*H + head] + ad));
        float w3 = __expf(lrelu(asrc[(size_t)j3*H + head] + ad));
        uint4 t0 = ((const uint4*)(h + (size_t)j0*HC))[ll];
        uint4 t1 = ((const uint4*)(h + (size_t)j1*HC))[ll];
        uint4 t2 = ((const uint4*)(h + (size_t)j2*HC))[ll];
        uint4 t3 = ((const uint4*)(h + (size_t)j3*HC))[ll];
        float f0[8], f1[8], f2[8], f3[8];
        unpack8(t0, f0); unpack8(t1, f1); unpack8(t2, f2); unpack8(t3, f3);
#pragma unroll
        for (int k=0;k<8;k++) acc[k] += w0*f0[k] + w1*f1[k] + w2*f2[k] + w3*f3[k];
        s += w0 + w1 + w2 + w3;
    }
    for (; e < e1; e += S){
        int j = csr_src[e];
        float w = __expf(lrelu(asrc[(size_t)j*H + head] + ad));
        uint4 t = ((const uint4*)(h + (size_t)j*HC))[ll];
        float f[8]; unpack8(t, f);
#pragma unroll
        for (int k=0;k<8;k++) acc[k] += w*f[k];
        s += w;
    }
#pragma unroll
    for (int m = CL; m < 64; m <<= 1){
        s += __shfl_xor(s, m, 64);
#pragma unroll
        for (int k=0;k<8;k++) acc[k] += __shfl_xor(acc[k], m, 64);
    }
    if (slot == 0){
        float inv = 1.f / s;
        float o[8];
#pragma unroll
        for (int k=0;k<8;k++) o[k] = fmaxf(acc[k]*inv + b[ll*8+k], 0.f);
        float4* dst0 = (float4*)(out + (size_t)i*ostride + ll*8);
        dst0[0] = make_float4(o[0],o[1],o[2],o[3]);
        dst0[1] = make_float4(o[4],o[5],o[6],o[7]);
    }
}

// ---------------- pooling + FC ----------------
__global__ void k_bounds(const int* __restrict__ batch, int* __restrict__ gstart, int n, int G){
    int g = threadIdx.x;
    if (g > G) return;
    int lo = 0, hi = n;
    while (lo < hi){ int mid = (lo+hi) >> 1; if (batch[mid] < g) lo = mid+1; else hi = mid; }
    gstart[g] = lo;
}

// node-parallel pooling, float4 loads: 128 threads cover 432 chans (108 quads)
__global__ void k_pool_sum(const float* __restrict__ xj, const int* __restrict__ batch,
                           float* __restrict__ pool){
    int nb = blockIdx.x * 32;
    int ne = min(nb + 32, NN);
    if (nb >= NN) return;
    int cq = threadIdx.x;              // quad index, 0..107 active of 128
    if (cq >= 108) return;
    float4 a = make_float4(0.f,0.f,0.f,0.f);
    int curg = batch[nb];
    for (int nn = nb; nn < ne; nn++){
        int g = batch[nn];
        if (g != curg){
            float* p = &pool[curg*432 + cq*4];
            atomicAdd(p+0, a.x); atomicAdd(p+1, a.y);
            atomicAdd(p+2, a.z); atomicAdd(p+3, a.w);
            a = make_float4(0.f,0.f,0.f,0.f); curg = g;
        }
        float4 v = *(const float4*)(xj + (size_t)nn*432 + cq*4);
        a.x += v.x; a.y += v.y; a.z += v.z; a.w += v.w;
    }
    float* p = &pool[curg*432 + cq*4];
    atomicAdd(p+0, a.x); atomicAdd(p+1, a.y);
    atomicAdd(p+2, a.z); atomicAdd(p+3, a.w);
}

__global__ void k_fc1(const float* __restrict__ pool, const int* __restrict__ gstart,
                      const float* __restrict__ W, const float* __restrict__ b,
                      float* __restrict__ hfc){
    int g = blockIdx.x, j = threadIdx.x;
    int cnt = gstart[g+1] - gstart[g];
    float invc = 1.f / (float)max(cnt, 1);
    float acc = 0.f;
    for (int k = 0; k < 432; k++) acc += pool[g*432 + k] * W[k*128 + j];
    hfc[g*128 + j] = fmaxf(acc * invc + b[j], 0.f);
}

__global__ void k_fc2(const float* __restrict__ hfc, const float* __restrict__ W,
                      const float* __restrict__ b, float* __restrict__ out){
    int g = blockIdx.x, t = threadIdx.x;
    float p = hfc[g*128 + t] * W[t];
    for (int off = 32; off > 0; off >>= 1) p += __shfl_down(p, off, 64);
    __shared__ float part[2];
    if ((t & 63) == 0) part[t >> 6] = p;
    __syncthreads();
    if (t == 0) out[g] = part[0] + part[1] + b[0];
}

extern "C" void kernel_launch(void* const* d_in, const int* in_sizes, int n_in,
                              void* d_out, int out_size, void* d_ws, size_t ws_size,
                              hipStream_t stream){
    const float* x     = (const float*)d_in[0];
    const int*   ei    = (const int*)  d_in[1];
    const int*   batch = (const int*)  d_in[2];
    const float* W1 = (const float*)d_in[3];  const float* b1 = (const float*)d_in[4];
    const float* W2 = (const float*)d_in[5];  const float* b2 = (const float*)d_in[6];
    const float* W3 = (const float*)d_in[7];
    const float* as3 = (const float*)d_in[8]; const float* ad3 = (const float*)d_in[9];
    const float* b3 = (const float*)d_in[10];
    const float* W4 = (const float*)d_in[11];
    const float* as4 = (const float*)d_in[12]; const float* ad4 = (const float*)d_in[13];
    const float* b4 = (const float*)d_in[14];
    const float* Wf1 = (const float*)d_in[15]; const float* bf1 = (const float*)d_in[16];
    const float* Wf2 = (const float*)d_in[17]; const float* bf2 = (const float*)d_in[18];
    float* out = (float*)d_out;

    const int* srcE = ei;
    const int* dstE = ei + NE;

    char* base = (char*)d_ws; size_t off = 0;
    auto alloc = [&](size_t bytes)->void*{
        void* p = base + off;
        off += (bytes + 255) & ~(size_t)255;
        return p;
    };
    int*   degi    = (int*)  alloc((size_t)NN*4);
    int*   cursor  = (int*)  alloc((size_t)NN*4);
    float* dinv    = (float*)alloc((size_t)NN*4);
    int*   rowptr  = (int*)  alloc((size_t)(NN+1)*4);
    int*   bsum    = (int*)  alloc(64*4);
    int*   csr_src = (int*)  alloc((size_t)NE*4);
    float* h_buf   = (float*)alloc((size_t)NN*128*4);   // fp32 h for GCN layers
    u16*   hb_buf  = (u16*)  alloc((size_t)NN*256*2);   // bf16 h for GAT layers
    float* xj      = (float*)alloc((size_t)NN*432*4);   // jump concat [x1|x2|x3|x4]
    float* a_src   = (float*)alloc((size_t)NN*8*4);
    float* a_dst   = (float*)alloc((size_t)NN*8*4);
    int*   gstart  = (int*)  alloc((size_t)(NG+1)*4);
    float* pool    = (float*)alloc((size_t)NG*432*4);
    float* hfc     = (float*)alloc((size_t)NG*128*4);

    hipMemsetAsync(degi, 0, (size_t)NN*4, stream);
    hipMemsetAsync(cursor, 0, (size_t)NN*4, stream);
    hipMemsetAsync(pool, 0, (size_t)NG*432*4, stream);

    const int EB = (NE + 255)/256;
    const int NB = (NN + 255)/256;
    const int SB = (NN + 1023)/1024;

    k_count  <<<EB, 256, 0, stream>>>(dstE, degi, NE);
    k_dinv   <<<NB, 256, 0, stream>>>(degi, dinv, NN);
    k_scan_a <<<SB, 256, 0, stream>>>(degi, rowptr, bsum, NN);
    k_scan_b <<<1, 64, 0, stream>>>(bsum, rowptr, SB, NN);
    k_scan_c <<<SB, 256, 0, stream>>>(rowptr, bsum, NN);
    k_scatter<<<EB, 256, 0, stream>>>(srcE, dstE, rowptr, cursor, csr_src, NE);

    // GCN layer 1
    k_mm<128,16> <<<(NN+15)/16, 256, 0, stream>>>(x, 128, W1, h_buf, NN);
    k_gcn_agg<16><<<(NN+15)/16, 256, 0, stream>>>(h_buf, dinv, rowptr, csr_src, b1, xj + 0, 432, NN);

    // GCN layer 2
    k_mm<16,32>  <<<(NN+7)/8, 256, 0, stream>>>(xj + 0, 432, W2, h_buf, NN);
    k_gcn_agg<32><<<(NN+15)/16, 256, 0, stream>>>(h_buf, dinv, rowptr, csr_src, b2, xj + 16, 432, NN);

    // GAT layer 3 (4 heads x 32), bf16 h
    k_mm_bf<32,128><<<(NN+1)/2, 256, 0, stream>>>(xj + 16, 432, W3, hb_buf, NN);
    k_att<4,32>  <<<(NN*4 + 255)/256, 256, 0, stream>>>(hb_buf, as3, ad3, a_src, a_dst, NN);
    k_gat_agg<4,32><<<(NN+3)/4, 256, 0, stream>>>(hb_buf, a_src, a_dst, rowptr, csr_src, b3, xj + 48, 432, NN);

    // GAT layer 4 (8 heads x 32), bf16 h
    {
        dim3 grid(4, (NN + 63)/64);
        k_mm4<<<grid, 256, 0, stream>>>(xj + 48, 432, W4, hb_buf, NN);
    }
    k_att<8,32>  <<<(NN*8 + 255)/256, 256, 0, stream>>>(hb_buf, as4, ad4, a_src, a_dst, NN);
    k_gat_agg<8,32><<<(NN+3)/4, 256, 0, stream>>>(hb_buf, a_src, a_dst, rowptr, csr_src, b4, xj + 176, 432, NN);

    // pooling + FC
    k_bounds<<<1, 256, 0, stream>>>(batch, gstart, NN, NG);
    k_pool_sum<<<(NN+31)/32, 128, 0, stream>>>(xj, batch, pool);
    k_fc1   <<<NG, 128, 0, stream>>>(pool, gstart, Wf1, bf1, hfc);
    k_fc2   <<<NG, 128, 0, stream>>>(hfc, Wf2, bf2, out);
}

// Round 8
// 507.009 us; speedup vs baseline: 1.0349x; 1.0349x over previous
//
#include <hip/hip_runtime.h>
#include <hip/hip_bf16.h>

#define NN 50000
#define NE 800000
#define NG 128

typedef unsigned short u16;

__device__ __forceinline__ float lrelu(float x){ return x > 0.f ? x : 0.2f*x; }
__device__ __forceinline__ u16 f2bf(float f){
    __hip_bfloat16 h = __float2bfloat16(f);
    return *(u16*)&h;
}
// unpack 8 bf16 (as uint4) -> 8 floats
__device__ __forceinline__ void unpack8(uint4 t, float* f){
    f[0]=__uint_as_float(t.x<<16); f[1]=__uint_as_float(t.x&0xffff0000u);
    f[2]=__uint_as_float(t.y<<16); f[3]=__uint_as_float(t.y&0xffff0000u);
    f[4]=__uint_as_float(t.z<<16); f[5]=__uint_as_float(t.z&0xffff0000u);
    f[6]=__uint_as_float(t.w<<16); f[7]=__uint_as_float(t.w&0xffff0000u);
}

// ---------------- CSR build ----------------
__global__ void k_count(const int* __restrict__ dst, int* __restrict__ degi, int E){
    int e = blockIdx.x*blockDim.x + threadIdx.x;
    if (e < E) atomicAdd(&degi[dst[e]], 1);
}

__global__ void k_dinv(const int* __restrict__ degi, float* __restrict__ dinv, int n){
    int i = blockIdx.x*blockDim.x + threadIdx.x;
    if (i < n) dinv[i] = rsqrtf((float)(degi[i] + 1));   // +1 = self loop
}

__global__ void k_scan_a(const int* __restrict__ deg, int* __restrict__ rowptr,
                         int* __restrict__ bsum, int n){
    __shared__ int lds[256];
    int base = blockIdx.x*1024 + threadIdx.x*4;
    int v[4]; int s = 0;
#pragma unroll
    for (int k=0;k<4;k++){ v[k] = (base+k < n) ? deg[base+k] : 0; s += v[k]; }
    lds[threadIdx.x] = s;
    __syncthreads();
    for (int off=1; off<256; off<<=1){
        int t = (threadIdx.x>=off) ? lds[threadIdx.x-off] : 0;
        __syncthreads(); lds[threadIdx.x] += t; __syncthreads();
    }
    int run = lds[threadIdx.x] - s;
#pragma unroll
    for (int k=0;k<4;k++){ if (base+k < n) rowptr[base+k] = run; run += v[k]; }
    if (threadIdx.x == 255) bsum[blockIdx.x] = lds[255];
}

__global__ void k_scan_b(int* __restrict__ bsum, int* __restrict__ rowptr, int nb, int n){
    __shared__ int lds[64];
    int s = (threadIdx.x < nb) ? bsum[threadIdx.x] : 0;
    lds[threadIdx.x] = s;
    __syncthreads();
    for (int off=1; off<64; off<<=1){
        int t = (threadIdx.x>=off) ? lds[threadIdx.x-off] : 0;
        __syncthreads(); lds[threadIdx.x] += t; __syncthreads();
    }
    if (threadIdx.x < nb) bsum[threadIdx.x] = lds[threadIdx.x] - s;
    if (threadIdx.x == 63) rowptr[n] = lds[63];
}

__global__ void k_scan_c(int* __restrict__ rowptr, const int* __restrict__ bsum, int n){
    int i = blockIdx.x*256 + threadIdx.x;
    int idx = i*4;
    int o = bsum[blockIdx.x];
#pragma unroll
    for (int k=0;k<4;k++) if (idx+k < n) rowptr[idx+k] += o;
}

__global__ void k_scatter(const int* __restrict__ src, const int* __restrict__ dst,
                          const int* __restrict__ rowptr, int* __restrict__ cursor,
                          int* __restrict__ csr_src, int E){
    int e = blockIdx.x*blockDim.x + threadIdx.x;
    if (e < E){
        int d = dst[e];
        int pos = rowptr[d] + atomicAdd(&cursor[d], 1);
        csr_src[pos] = src[e];
    }
}

// ---------------- small matmul (fp32 out) ----------------
template<int K, int M>
__global__ void k_mm(const float* __restrict__ in, int istride,
                     const float* __restrict__ W, float* __restrict__ out, int n){
    __shared__ float wl[K*M];
    for (int i = threadIdx.x; i < K*M; i += blockDim.x) wl[i] = W[i];
    __syncthreads();
    constexpr int NPB = 256 / M;
    int m  = threadIdx.x % M;
    int nl = threadIdx.x / M;
    int node = blockIdx.x * NPB + nl;
    if (node >= n) return;
    const float* row = in + (size_t)node * istride;
    float acc = 0.f;
#pragma unroll 8
    for (int k = 0; k < K; k++) acc += row[k] * wl[k*M + m];
    out[(size_t)node*M + m] = acc;
}

// mm3 + fused att epilogue: out bf16 [N,128], a_src/a_dst [N,4] from fp32 acc
__global__ void k_mm_bf_att(const float* __restrict__ in, int istride,
                            const float* __restrict__ W,
                            const float* __restrict__ as, const float* __restrict__ adt,
                            u16* __restrict__ out, float* __restrict__ asrc,
                            float* __restrict__ adst, int n){
    constexpr int K = 32, M = 128;
    __shared__ float wl[K*M];
    for (int i = threadIdx.x; i < K*M; i += 256) wl[i] = W[i];
    __syncthreads();
    int m  = threadIdx.x % M;
    int nl = threadIdx.x / M;   // 2 nodes per block
    int node = blockIdx.x * 2 + nl;
    if (node >= n) return;
    const float* row = in + (size_t)node * istride;
    float acc = 0.f;
#pragma unroll 8
    for (int k = 0; k < K; k++) acc += row[k] * wl[k*M + m];
    out[(size_t)node*M + m] = f2bf(acc);
    // attention partials from fp32 acc; head = m>>5 spans 32 contiguous lanes
    float psv = acc * as[m];
    float pdv = acc * adt[m];
#pragma unroll
    for (int mm = 1; mm <= 16; mm <<= 1){
        psv += __shfl_xor(psv, mm, 64);
        pdv += __shfl_xor(pdv, mm, 64);
    }
    if ((m & 31) == 0){
        int hh = m >> 5;
        asrc[(size_t)node*4 + hh] = psv;
        adst[(size_t)node*4 + hh] = pdv;
    }
}

// ---------------- mm4: [N,128] @ [128,256] -> bf16 h + fused att logits ----------------
__global__ void k_mm4(const float* __restrict__ in, int istride,
                      const float* __restrict__ W,
                      const float* __restrict__ as, const float* __restrict__ adt,
                      u16* __restrict__ hb, float* __restrict__ asrc,
                      float* __restrict__ adst, int n){
    __shared__ __align__(16) float xs[64][68];
    __shared__ __align__(16) float ws[64][68];
    int tid = threadIdx.x;
    int tx = tid & 15;
    int ty = tid >> 4;
    int nbase = blockIdx.y * 64;
    int cbase = blockIdx.x * 64;
    float acc[4][4] = {};
    for (int kb = 0; kb < 128; kb += 64){
#pragma unroll
        for (int p = 0; p < 4; p++){
            int r = p*16 + ty;
            int nn = nbase + r;
            float4 v = make_float4(0.f,0.f,0.f,0.f);
            if (nn < n) v = *(const float4*)(in + (size_t)nn*istride + kb + tx*4);
            *(float4*)&xs[r][tx*4] = v;
            float4 wv = *(const float4*)(W + (size_t)(kb + r)*256 + cbase + tx*4);
            *(float4*)&ws[r][tx*4] = wv;
        }
        __syncthreads();
#pragma unroll 16
        for (int k = 0; k < 64; k++){
            float4 wv = *(const float4*)&ws[k][tx*4];
#pragma unroll
            for (int i2 = 0; i2 < 4; i2++){
                float a = xs[ty*4 + i2][k];
                acc[i2][0] += a*wv.x; acc[i2][1] += a*wv.y;
                acc[i2][2] += a*wv.z; acc[i2][3] += a*wv.w;
            }
        }
        __syncthreads();
    }
    // head owned by this thread's 4 cols
    int ht = (cbase >> 5) + (tx >> 3);
    int co = (tx & 7) * 4;
    float s0 = as[ht*32+co+0], s1 = as[ht*32+co+1], s2 = as[ht*32+co+2], s3 = as[ht*32+co+3];
    float d0 = adt[ht*32+co+0], d1 = adt[ht*32+co+1], d2 = adt[ht*32+co+2], d3 = adt[ht*32+co+3];
    float ps[4], pd[4];
#pragma unroll
    for (int i2 = 0; i2 < 4; i2++){
        ps[i2] = acc[i2][0]*s0 + acc[i2][1]*s1 + acc[i2][2]*s2 + acc[i2][3]*s3;
        pd[i2] = acc[i2][0]*d0 + acc[i2][1]*d1 + acc[i2][2]*d2 + acc[i2][3]*d3;
    }
#pragma unroll
    for (int mm = 1; mm <= 4; mm <<= 1){
#pragma unroll
        for (int i2 = 0; i2 < 4; i2++){
            ps[i2] += __shfl_xor(ps[i2], mm, 64);
            pd[i2] += __shfl_xor(pd[i2], mm, 64);
        }
    }
#pragma unroll
    for (int i2 = 0; i2 < 4; i2++){
        int nn = nbase + ty*4 + i2;
        if (nn < n){
            ushort4 v;
            v.x = f2bf(acc[i2][0]); v.y = f2bf(acc[i2][1]);
            v.z = f2bf(acc[i2][2]); v.w = f2bf(acc[i2][3]);
            *(ushort4*)(hb + (size_t)nn*256 + cbase + tx*4) = v;
            if ((tx & 7) == 0){
                asrc[(size_t)nn*8 + ht] = ps[i2];
                adst[(size_t)nn*8 + ht] = pd[i2];
            }
        }
    }
}

// ---------------- GCN aggregation: 16 lanes/node, edge loop unrolled x4 ----------------
template<int C>
__global__ void k_gcn_agg(const float* __restrict__ h, const float* __restrict__ dinv,
                          const int* __restrict__ rowptr, const int* __restrict__ csr_src,
                          const float* __restrict__ b, float* __restrict__ out,
                          int ostride, int n){
    constexpr int CL = C/4;
    constexpr int S  = 16/CL;
    int lin = threadIdx.x & 15;
    int i = blockIdx.x*16 + (threadIdx.x >> 4);
    if (i >= n) return;
    int ll = lin % CL, slot = lin / CL;
    float di = dinv[i];
    float acc[4] = {0.f,0.f,0.f,0.f};
    if (slot == 0){
        float4 t = ((const float4*)(h + (size_t)i*C))[ll];
        acc[0]=di*t.x; acc[1]=di*t.y; acc[2]=di*t.z; acc[3]=di*t.w;
    }
    int e0 = rowptr[i], e1 = rowptr[i+1];
    int e = e0 + slot;
    for (; e + 3*S < e1; e += 4*S){
        int j0 = csr_src[e], j1 = csr_src[e+S], j2 = csr_src[e+2*S], j3 = csr_src[e+3*S];
        float d0 = dinv[j0], d1 = dinv[j1], d2 = dinv[j2], d3 = dinv[j3];
        float4 t0 = ((const float4*)(h + (size_t)j0*C))[ll];
        float4 t1 = ((const float4*)(h + (size_t)j1*C))[ll];
        float4 t2 = ((const float4*)(h + (size_t)j2*C))[ll];
        float4 t3 = ((const float4*)(h + (size_t)j3*C))[ll];
        acc[0]+=d0*t0.x+d1*t1.x+d2*t2.x+d3*t3.x;
        acc[1]+=d0*t0.y+d1*t1.y+d2*t2.y+d3*t3.y;
        acc[2]+=d0*t0.z+d1*t1.z+d2*t2.z+d3*t3.z;
        acc[3]+=d0*t0.w+d1*t1.w+d2*t2.w+d3*t3.w;
    }
    for (; e < e1; e += S){
        int j = csr_src[e];
        float dj = dinv[j];
        float4 t = ((const float4*)(h + (size_t)j*C))[ll];
        acc[0]+=dj*t.x; acc[1]+=dj*t.y; acc[2]+=dj*t.z; acc[3]+=dj*t.w;
    }
#pragma unroll
    for (int m = CL; m < 16; m <<= 1){
#pragma unroll
        for (int k=0;k<4;k++) acc[k] += __shfl_xor(acc[k], m, 64);
    }
    if (slot == 0){
        float4 o;
        o.x = fmaxf(di*acc[0] + b[ll*4+0], 0.f);
        o.y = fmaxf(di*acc[1] + b[ll*4+1], 0.f);
        o.z = fmaxf(di*acc[2] + b[ll*4+2], 0.f);
        o.w = fmaxf(di*acc[3] + b[ll*4+3], 0.f);
        *(float4*)(out + (size_t)i*ostride + ll*4) = o;
    }
}

// ---------------- GAT agg layer 3 (bf16 h, H=4, C=32): wave/node, unroll x4 ----------------
__global__ void k_gat_agg3(const u16* __restrict__ h, const float* __restrict__ asrc,
                           const float* __restrict__ adst, const int* __restrict__ rowptr,
                           const int* __restrict__ csr_src, const float* __restrict__ b,
                           float* __restrict__ out, int ostride, int n){
    constexpr int HC = 128, CL = 16, S = 4;
    int lane = threadIdx.x & 63;
    int wid  = threadIdx.x >> 6;
    int i = blockIdx.x*4 + wid;
    if (i >= n) return;
    int ll   = lane % CL;
    int slot = lane / CL;
    int head = (ll*8)/32;
    float ad = adst[(size_t)i*4 + head];
    float acc[8] = {0.f,0.f,0.f,0.f,0.f,0.f,0.f,0.f};
    float s = 0.f;
    if (slot == 0){
        float wself = __expf(lrelu(asrc[(size_t)i*4 + head] + ad));
        uint4 t = ((const uint4*)(h + (size_t)i*HC))[ll];
        float f[8]; unpack8(t, f);
#pragma unroll
        for (int k=0;k<8;k++) acc[k] = wself*f[k];
        s = wself;
    }
    int e0 = rowptr[i], e1 = rowptr[i+1];
    int e = e0 + slot;
    for (; e + 3*S < e1; e += 4*S){
        int j0 = csr_src[e], j1 = csr_src[e+S], j2 = csr_src[e+2*S], j3 = csr_src[e+3*S];
        float w0 = __expf(lrelu(asrc[(size_t)j0*4 + head] + ad));
        float w1 = __expf(lrelu(asrc[(size_t)j1*4 + head] + ad));
        float w2 = __expf(lrelu(asrc[(size_t)j2*4 + head] + ad));
        float w3 = __expf(lrelu(asrc[(size_t)j3*4 + head] + ad));
        uint4 t0 = ((const uint4*)(h + (size_t)j0*HC))[ll];
        uint4 t1 = ((const uint4*)(h + (size_t)j1*HC))[ll];
        uint4 t2 = ((const uint4*)(h + (size_t)j2*HC))[ll];
        uint4 t3 = ((const uint4*)(h + (size_t)j3*HC))[ll];
        float f0[8], f1[8], f2[8], f3[8];
        unpack8(t0, f0); unpack8(t1, f1); unpack8(t2, f2); unpack8(t3, f3);
#pragma unroll
        for (int k=0;k<8;k++) acc[k] += w0*f0[k] + w1*f1[k] + w2*f2[k] + w3*f3[k];
        s += w0 + w1 + w2 + w3;
    }
    for (; e < e1; e += S){
        int j = csr_src[e];
        float w = __expf(lrelu(asrc[(size_t)j*4 + head] + ad));
        uint4 t = ((const uint4*)(h + (size_t)j*HC))[ll];
        float f[8]; unpack8(t, f);
#pragma unroll
        for (int k=0;k<8;k++) acc[k] += w*f[k];
        s += w;
    }
#pragma unroll
    for (int m = CL; m < 64; m <<= 1){
        s += __shfl_xor(s, m, 64);
#pragma unroll
        for (int k=0;k<8;k++) acc[k] += __shfl_xor(acc[k], m, 64);
    }
    if (slot == 0){
        float inv = 1.f / s;
        float o[8];
#pragma unroll
        for (int k=0;k<8;k++) o[k] = fmaxf(acc[k]*inv + b[ll*8+k], 0.f);
        float4* dst0 = (float4*)(out + (size_t)i*ostride + ll*8);
        dst0[0] = make_float4(o[0],o[1],o[2],o[3]);
        dst0[1] = make_float4(o[4],o[5],o[6],o[7]);
    }
}

// ---------------- GAT agg layer 4 (bf16 h, H=8, C=32): wave/node, unroll x4 ----------------
__global__ void k_gat_agg4(const u16* __restrict__ h, const float* __restrict__ asrc,
                           const float* __restrict__ adst, const int* __restrict__ rowptr,
                           const int* __restrict__ csr_src, const float* __restrict__ b,
                           float* __restrict__ out, int ostride, int n){
    constexpr int HC = 256, CL = 32, S = 2;
    int lane = threadIdx.x & 63;
    int wid  = threadIdx.x >> 6;
    int i = blockIdx.x*4 + wid;
    if (i >= n) return;
    int ll   = lane % CL;
    int slot = lane / CL;
    int head = ll >> 2;
    float ad = adst[(size_t)i*8 + head];
    float acc[8] = {0.f,0.f,0.f,0.f,0.f,0.f,0.f,0.f};
    float s = 0.f;
    if (slot == 0){
        float wself = __expf(lrelu(asrc[(size_t)i*8 + head] + ad));
        uint4 t = ((const uint4*)(h + (size_t)i*HC))[ll];
        float f[8]; unpack8(t, f);
#pragma unroll
        for (int k=0;k<8;k++) acc[k] = wself*f[k];
        s = wself;
    }
    int e0 = rowptr[i], e1 = rowptr[i+1];
    int e = e0 + slot;
    for (; e + 3*S < e1; e += 4*S){
        int j0 = csr_src[e], j1 = csr_src[e+S], j2 = csr_src[e+2*S], j3 = csr_src[e+3*S];
        float w0 = __expf(lrelu(asrc[(size_t)j0*8 + head] + ad));
        float w1 = __expf(lrelu(asrc[(size_t)j1*8 + head] + ad));
        float w2 = __expf(lrelu(asrc[(size_t)j2*8 + head] + ad));
        float w3 = __expf(lrelu(asrc[(size_t)j3*8 + head] + ad));
        uint4 t0 = ((const uint4*)(h + (size_t)j0*HC))[ll];
        uint4 t1 = ((const uint4*)(h + (size_t)j1*HC))[ll];
        uint4 t2 = ((const uint4*)(h + (size_t)j2*HC))[ll];
        uint4 t3 = ((const uint4*)(h + (size_t)j3*HC))[ll];
        float f0[8], f1[8], f2[8], f3[8];
        unpack8(t0, f0); unpack8(t1, f1); unpack8(t2, f2); unpack8(t3, f3);
#pragma unroll
        for (int k=0;k<8;k++) acc[k] += w0*f0[k] + w1*f1[k] + w2*f2[k] + w3*f3[k];
        s += w0 + w1 + w2 + w3;
    }
    for (; e < e1; e += S){
        int j = csr_src[e];
        float w = __expf(lrelu(asrc[(size_t)j*8 + head] + ad));
        uint4 t = ((const uint4*)(h + (size_t)j*HC))[ll];
        float f[8]; unpack8(t, f);
#pragma unroll
        for (int k=0;k<8;k++) acc[k] += w*f[k];
        s += w;
    }
    // CL=32 -> single xor step
    s += __shfl_xor(s, 32, 64);
#pragma unroll
    for (int k=0;k<8;k++) acc[k] += __shfl_xor(acc[k], 32, 64);
    if (slot == 0){
        float inv = 1.f / s;
        float o[8];
#pragma unroll
        for (int k=0;k<8;k++) o[k] = fmaxf(acc[k]*inv + b[ll*8+k], 0.f);
        float4* dst0 = (float4*)(out + (size_t)i*ostride + ll*8);
        dst0[0] = make_float4(o[0],o[1],o[2],o[3]);
        dst0[1] = make_float4(o[4],o[5],o[6],o[7]);
    }
}

// ---------------- pooling + FC ----------------
__global__ void k_bounds(const int* __restrict__ batch, int* __restrict__ gstart, int n, int G){
    int g = threadIdx.x;
    if (g > G) return;
    int lo = 0, hi = n;
    while (lo < hi){ int mid = (lo+hi) >> 1; if (batch[mid] < g) lo = mid+1; else hi = mid; }
    gstart[g] = lo;
}

__global__ void k_pool_sum(const float* __restrict__ xj, const int* __restrict__ batch,
                           float* __restrict__ pool){
    int nb = blockIdx.x * 32;
    int ne = min(nb + 32, NN);
    if (nb >= NN) return;
    int cq = threadIdx.x;
    if (cq >= 108) return;
    float4 a = make_float4(0.f,0.f,0.f,0.f);
    int curg = batch[nb];
    for (int nn = nb; nn < ne; nn++){
        int g = batch[nn];
        if (g != curg){
            float* p = &pool[curg*432 + cq*4];
            atomicAdd(p+0, a.x); atomicAdd(p+1, a.y);
            atomicAdd(p+2, a.z); atomicAdd(p+3, a.w);
            a = make_float4(0.f,0.f,0.f,0.f); curg = g;
        }
        float4 v = *(const float4*)(xj + (size_t)nn*432 + cq*4);
        a.x += v.x; a.y += v.y; a.z += v.z; a.w += v.w;
    }
    float* p = &pool[curg*432 + cq*4];
    atomicAdd(p+0, a.x); atomicAdd(p+1, a.y);
    atomicAdd(p+2, a.z); atomicAdd(p+3, a.w);
}

__global__ void k_fc1(const float* __restrict__ pool, const int* __restrict__ gstart,
                      const float* __restrict__ W, const float* __restrict__ b,
                      float* __restrict__ hfc){
    int g = blockIdx.x, j = threadIdx.x;
    int cnt = gstart[g+1] - gstart[g];
    float invc = 1.f / (float)max(cnt, 1);
    float acc = 0.f;
    for (int k = 0; k < 432; k++) acc += pool[g*432 + k] * W[k*128 + j];
    hfc[g*128 + j] = fmaxf(acc * invc + b[j], 0.f);
}

__global__ void k_fc2(const float* __restrict__ hfc, const float* __restrict__ W,
                      const float* __restrict__ b, float* __restrict__ out){
    int g = blockIdx.x, t = threadIdx.x;
    float p = hfc[g*128 + t] * W[t];
    for (int off = 32; off > 0; off >>= 1) p += __shfl_down(p, off, 64);
    __shared__ float part[2];
    if ((t & 63) == 0) part[t >> 6] = p;
    __syncthreads();
    if (t == 0) out[g] = part[0] + part[1] + b[0];
}

extern "C" void kernel_launch(void* const* d_in, const int* in_sizes, int n_in,
                              void* d_out, int out_size, void* d_ws, size_t ws_size,
                              hipStream_t stream){
    const float* x     = (const float*)d_in[0];
    const int*   ei    = (const int*)  d_in[1];
    const int*   batch = (const int*)  d_in[2];
    const float* W1 = (const float*)d_in[3];  const float* b1 = (const float*)d_in[4];
    const float* W2 = (const float*)d_in[5];  const float* b2 = (const float*)d_in[6];
    const float* W3 = (const float*)d_in[7];
    const float* as3 = (const float*)d_in[8]; const float* ad3 = (const float*)d_in[9];
    const float* b3 = (const float*)d_in[10];
    const float* W4 = (const float*)d_in[11];
    const float* as4 = (const float*)d_in[12]; const float* ad4 = (const float*)d_in[13];
    const float* b4 = (const float*)d_in[14];
    const float* Wf1 = (const float*)d_in[15]; const float* bf1 = (const float*)d_in[16];
    const float* Wf2 = (const float*)d_in[17]; const float* bf2 = (const float*)d_in[18];
    float* out = (float*)d_out;

    const int* srcE = ei;
    const int* dstE = ei + NE;

    char* base = (char*)d_ws; size_t off = 0;
    auto alloc = [&](size_t bytes)->void*{
        void* p = base + off;
        off += (bytes + 255) & ~(size_t)255;
        return p;
    };
    int*   degi    = (int*)  alloc((size_t)NN*4);
    int*   cursor  = (int*)  alloc((size_t)NN*4);
    float* dinv    = (float*)alloc((size_t)NN*4);
    int*   rowptr  = (int*)  alloc((size_t)(NN+1)*4);
    int*   bsum    = (int*)  alloc(64*4);
    int*   csr_src = (int*)  alloc((size_t)NE*4);
    float* h_buf   = (float*)alloc((size_t)NN*128*4);   // fp32 h for GCN layers
    u16*   hb3     = (u16*)  alloc((size_t)NN*128*2);   // bf16 h3
    u16*   hb4     = (u16*)  alloc((size_t)NN*256*2);   // bf16 h4
    float* xj      = (float*)alloc((size_t)NN*432*4);   // jump concat [x1|x2|x3|x4]
    float* a_src   = (float*)alloc((size_t)NN*8*4);
    float* a_dst   = (float*)alloc((size_t)NN*8*4);
    int*   gstart  = (int*)  alloc((size_t)(NG+1)*4);
    float* pool    = (float*)alloc((size_t)NG*432*4);
    float* hfc     = (float*)alloc((size_t)NG*128*4);

    hipMemsetAsync(degi, 0, (size_t)NN*4, stream);
    hipMemsetAsync(cursor, 0, (size_t)NN*4, stream);
    hipMemsetAsync(pool, 0, (size_t)NG*432*4, stream);

    const int EB = (NE + 255)/256;
    const int NB = (NN + 255)/256;
    const int SB = (NN + 1023)/1024;

    k_count  <<<EB, 256, 0, stream>>>(dstE, degi, NE);
    k_dinv   <<<NB, 256, 0, stream>>>(degi, dinv, NN);
    k_scan_a <<<SB, 256, 0, stream>>>(degi, rowptr, bsum, NN);
    k_scan_b <<<1, 64, 0, stream>>>(bsum, rowptr, SB, NN);
    k_scan_c <<<SB, 256, 0, stream>>>(rowptr, bsum, NN);
    k_scatter<<<EB, 256, 0, stream>>>(srcE, dstE, rowptr, cursor, csr_src, NE);

    // GCN layer 1
    k_mm<128,16> <<<(NN+15)/16, 256, 0, stream>>>(x, 128, W1, h_buf, NN);
    k_gcn_agg<16><<<(NN+15)/16, 256, 0, stream>>>(h_buf, dinv, rowptr, csr_src, b1, xj + 0, 432, NN);

    // GCN layer 2
    k_mm<16,32>  <<<(NN+7)/8, 256, 0, stream>>>(xj + 0, 432, W2, h_buf, NN);
    k_gcn_agg<32><<<(NN+15)/16, 256, 0, stream>>>(h_buf, dinv, rowptr, csr_src, b2, xj + 16, 432, NN);

    // GAT layer 3 (4 heads x 32): mm + fused att logits, bf16 h
    k_mm_bf_att<<<(NN+1)/2, 256, 0, stream>>>(xj + 16, 432, W3, as3, ad3, hb3, a_src, a_dst, NN);
    k_gat_agg3<<<(NN+3)/4, 256, 0, stream>>>(hb3, a_src, a_dst, rowptr, csr_src, b3, xj + 48, 432, NN);

    // GAT layer 4 (8 heads x 32): mm4 + fused att logits, bf16 h
    {
        dim3 grid(4, (NN + 63)/64);
        k_mm4<<<grid, 256, 0, stream>>>(xj + 48, 432, W4, as4, ad4, hb4, a_src, a_dst, NN);
    }
    k_gat_agg4<<<(NN+3)/4, 256, 0, stream>>>(hb4, a_src, a_dst, rowptr, csr_src, b4, xj + 176, 432, NN);

    // pooling + FC
    k_bounds<<<1, 256, 0, stream>>>(batch, gstart, NN, NG);
    k_pool_sum<<<(NN+31)/32, 128, 0, stream>>>(xj, batch, pool);
    k_fc1   <<<NG, 128, 0, stream>>>(pool, gstart, Wf1, bf1, hfc);
    k_fc2   <<<NG, 128, 0, stream>>>(hfc, Wf2, bf2, out);
}